// Round 6
// baseline (1855.254 us; speedup 1.0000x reference)
//
#include <hip/hip_runtime.h>

// SubsetGFlowNetTB: 17-step GFlowNet trajectory-balance forward.
// R6 key insight: the recurrent state depends ONLY on `actions`, so steps are
// independent once per-(sample,t) metadata is precomputed. Process 2 steps per
// chunk (64-row tiles): weight L2 traffic halves (384KB/chunk covers 64 rows),
// barriers halve (4 per 2 steps). Phase B single-pass 4-acc (64 AGPR, proven
// 192-reg budget at 2 waves/SIMD); phase C 4 passes of 2-acc. selmask(t+1)
// handled via a register patch column; selw committed once per chunk.

#define NEG_INF (-1000000000.0f)
#define LOG2E 1.4426950408889634f
#define LN2   0.6931471805599453f

// meta2 bits: [9:0] action, [10] alive, [11] stop, [12] isnew, [13] full, [20:16] kcnt
#define M_ALIVE (1 << 10)
#define M_STOP  (1 << 11)
#define M_NEW   (1 << 12)
#define M_FULL  (1 << 13)
#define M_KSH   16

typedef short bf16x8 __attribute__((ext_vector_type(8)));
typedef float f32x16 __attribute__((ext_vector_type(16)));

__device__ __forceinline__ unsigned short f2bf(float x){
  unsigned int u = __float_as_uint(x);
  u = (u + 0x7FFFu + ((u >> 16) & 1u)) >> 16;   // RNE
  return (unsigned short)u;
}
__device__ __forceinline__ float bf2f(unsigned short h){
  return __uint_as_float(((unsigned int)h) << 16);
}
__device__ __forceinline__ unsigned int cvt_pk_bf16(float lo, float hi){
  unsigned int r;
  asm("v_cvt_pk_bf16_f32 %0, %1, %2" : "=v"(r) : "v"(lo), "v"(hi));
  return r;
}

// ---------------------------------------------------------------------------
// Prep: W2 (256x256 f32), Wh (256x513 f32) -> bf16 MFMA fragments.
// Fragment: lane l of tile (kt,ntg) holds M[kt*16+(l>>5)*8+i][ntg*32+(l&31)].
// whf is PRE-SCALED by log2(e) so phase C can use v_exp2 directly.
// ---------------------------------------------------------------------------
__global__ void prep_kernel(const float* __restrict__ W2, const float* __restrict__ Wh,
                            unsigned short* __restrict__ w2f, unsigned short* __restrict__ whf,
                            float* __restrict__ whstop){
  int id = blockIdx.x * 256 + threadIdx.x;
  if (id < 8192){                       // W2 fragments
    int lane = id & 63; int tile = id >> 6;   // tile = kt*8 + ntg
    int ntg = tile & 7, kt = tile >> 3;
    int col = ntg * 32 + (lane & 31);
    int k0  = kt * 16 + (lane >> 5) * 8;
    unsigned int u[4];
#pragma unroll
    for (int p = 0; p < 4; ++p){
      unsigned short lo = f2bf(W2[(k0 + 2*p    ) * 256 + col]);
      unsigned short hi = f2bf(W2[(k0 + 2*p + 1) * 256 + col]);
      u[p] = (unsigned int)lo | ((unsigned int)hi << 16);
    }
    *(uint4*)(w2f + (size_t)id * 8) = make_uint4(u[0], u[1], u[2], u[3]);
  } else if (id < 24576){               // Wh fragments (asset cols 0..511), x log2e
    int id2 = id - 8192;
    int lane = id2 & 63; int tile = id2 >> 6; // tile = kt*16 + ntg
    int ntg = tile & 15, kt = tile >> 4;
    int col = ntg * 32 + (lane & 31);
    int k0  = kt * 16 + (lane >> 5) * 8;
    unsigned int u[4];
#pragma unroll
    for (int p = 0; p < 4; ++p){
      unsigned short lo = f2bf(Wh[(k0 + 2*p    ) * 513 + col] * LOG2E);
      unsigned short hi = f2bf(Wh[(k0 + 2*p + 1) * 513 + col] * LOG2E);
      u[p] = (unsigned int)lo | ((unsigned int)hi << 16);
    }
    *(uint4*)(whf + (size_t)id2 * 8) = make_uint4(u[0], u[1], u[2], u[3]);
  } else if (id < 24832){               // stop column, f32, unscaled
    int k = id - 24576;
    whstop[k] = Wh[k * 513 + 512];
  }
}

// ---------------------------------------------------------------------------
// Fused kernel: 256 threads (4 waves) own 32 samples, 9 chunks x 2 steps.
// h tiles [64 rows][256 feats] bf16: rows 0-31 = step t, 32-63 = step t+1.
// Byte-XOR swizzle ((row&15)<<4).
// ---------------------------------------------------------------------------
__launch_bounds__(256, 2)
__global__ void gfn_kernel(const int* __restrict__ actions, const float* __restrict__ rp,
                           const float* __restrict__ W1, const float* __restrict__ b1,
                           const float* __restrict__ b2, const float* __restrict__ bh,
                           const unsigned short* __restrict__ w2f,
                           const unsigned short* __restrict__ whf,
                           const float* __restrict__ whstop,
                           float* __restrict__ out)
{
  __shared__ alignas(16) unsigned short h1[64 * 256];   // 32 KB
  __shared__ alignas(16) unsigned short h2[64 * 256];   // 32 KB
  __shared__ alignas(16) float c_lds[1024];             // W1 rows 512..514 + b1
  __shared__ alignas(16) float b2s[256];
  __shared__ alignas(16) float ebh[512];                // exp(bh[col]), plain order
  __shared__ alignas(16) unsigned short whst_h[256];    // stop col, bf16
  __shared__ unsigned long long selw[32][9];            // pad 9
  __shared__ float pred_s[64][5];                       // pad 5
  __shared__ float stopl[64];
  __shared__ float chosen[64];
  __shared__ float logpf_s[32];
  __shared__ float rp_s[32];
  __shared__ int   meta2[18][32];

  const int tid  = threadIdx.x;
  const int wave = tid >> 6;            // 0..3
  const int lane = tid & 63;
  const int ln5  = lane & 31;
  const int lg2  = lane >> 5;
  const int base = blockIdx.x * 32;

  // ---- init ----
  for (int i = tid; i < 1024; i += 256){
    int rrow = i >> 8, f = i & 255;
    c_lds[i] = (rrow < 3) ? W1[(512 + rrow) * 256 + f] : b1[f];
  }
  b2s[tid] = b2[tid];
  whst_h[tid] = f2bf(whstop[tid]);
  for (int i = tid; i < 512; i += 256) ebh[i] = __expf(bh[i]);
  const float stopbias = bh[512];
  for (int i = tid; i < 288; i += 256) ((unsigned long long*)selw)[i] = 0ULL;
  int* acts = (int*)h1;                 // stage actions in h1 scratch
  for (int i = tid; i < 544; i += 256) acts[i] = actions[base * 17 + i];
  if (tid < 32){ logpf_s[tid] = 0.f; rp_s[tid] = rp[base + tid]; }
  __syncthreads();

  // ---- state precompute: O(17^2) scan per sample; no GEMM dependency ----
  if (tid < 32){
    int s = tid, k = 0;
    for (int t = 0; t < 17; ++t){
      int a = acts[s * 17 + t];
      bool alive  = (a >= 0);
      bool isstop = (a == 512);
      bool isnew  = alive && (a < 512);
      if (isnew){
        for (int u = 0; u < t; ++u) if (acts[s * 17 + u] == a){ isnew = false; break; }
      }
      meta2[t][s] = (a & 1023) | (alive ? M_ALIVE : 0) | (isstop ? M_STOP : 0)
                  | (isnew ? M_NEW : 0) | ((k >= 16) ? M_FULL : 0) | (k << M_KSH);
      if (isnew) ++k;
    }
    meta2[17][s] = 1023 | ((k >= 16) ? M_FULL : 0) | (k << M_KSH);  // dummy step
  }
  float S[32];
#pragma unroll
  for (int j = 0; j < 32; ++j) S[j] = 0.f;
  __syncthreads();

  char* h1b = (char*)h1;
  char* h2b = (char*)h2;

#pragma unroll 1
  for (int c = 0; c < 9; ++c){
    const int t = c * 2;

    // ---- Phase A: h1 rows for steps t and t+1; thread=(4 feats, 8 samples) ----
    {
      const float4 ck4 = *(const float4*)&c_lds[lane * 4];
      const float4 ct4 = *(const float4*)&c_lds[256 + lane * 4];
      const float4 cr4 = *(const float4*)&c_lds[512 + lane * 4];
      const float4 cb4 = *(const float4*)&c_lds[768 + lane * 4];
      float tf = (float)t;
      float c00 = cb4.x + tf * ct4.x, c01 = cb4.y + tf * ct4.y;
      float c02 = cb4.z + tf * ct4.z, c03 = cb4.w + tf * ct4.w;
      float c10 = c00 + ct4.x, c11 = c01 + ct4.y, c12 = c02 + ct4.z, c13 = c03 + ct4.w;
#pragma unroll
      for (int s8 = 0; s8 < 8; ++s8){
        int s = wave * 8 + s8;
        float rv = rp_s[s];
        int m0 = meta2[t][s];
        float kf = (float)((m0 >> M_KSH) & 31);
        {
          float v0 = fmaxf(S[s8*4+0] + kf * ck4.x + rv * cr4.x + c00, 0.f);
          float v1 = fmaxf(S[s8*4+1] + kf * ck4.y + rv * cr4.y + c01, 0.f);
          float v2 = fmaxf(S[s8*4+2] + kf * ck4.z + rv * cr4.z + c02, 0.f);
          float v3 = fmaxf(S[s8*4+3] + kf * ck4.w + rv * cr4.w + c03, 0.f);
          int byte = (s * 512 + lane * 8) ^ ((s & 15) << 4);
          *(uint2*)(h1b + byte) = make_uint2(cvt_pk_bf16(v0, v1), cvt_pk_bf16(v2, v3));
        }
        if (m0 & M_NEW){
          int a = m0 & 1023;
          float4 w = *(const float4*)(W1 + (size_t)a * 256 + lane * 4);
          S[s8*4+0] += w.x; S[s8*4+1] += w.y; S[s8*4+2] += w.z; S[s8*4+3] += w.w;
        }
        int m1 = meta2[t + 1][s];
        float kf1 = (float)((m1 >> M_KSH) & 31);
        {
          float v0 = fmaxf(S[s8*4+0] + kf1 * ck4.x + rv * cr4.x + c10, 0.f);
          float v1 = fmaxf(S[s8*4+1] + kf1 * ck4.y + rv * cr4.y + c11, 0.f);
          float v2 = fmaxf(S[s8*4+2] + kf1 * ck4.z + rv * cr4.z + c12, 0.f);
          float v3 = fmaxf(S[s8*4+3] + kf1 * ck4.w + rv * cr4.w + c13, 0.f);
          int byte = ((32 + s) * 512 + lane * 8) ^ ((s & 15) << 4);
          *(uint2*)(h1b + byte) = make_uint2(cvt_pk_bf16(v0, v1), cvt_pk_bf16(v2, v3));
        }
        if (m1 & M_NEW){
          int a = m1 & 1023;
          float4 w = *(const float4*)(W1 + (size_t)a * 256 + lane * 4);
          S[s8*4+0] += w.x; S[s8*4+1] += w.y; S[s8*4+2] += w.z; S[s8*4+3] += w.w;
        }
      }
    }
    __syncthreads();

    // ---- Phase B (swapped): D'[feat][row], wave owns feats [wave*64,+64) ----
    {
      f32x16 a00, a01, a10, a11;   // [feat-tile][row-tile]
#pragma unroll
      for (int i = 0; i < 16; ++i){ a00[i]=0.f; a01[i]=0.f; a10[i]=0.f; a11[i]=0.f; }
#pragma unroll 4
      for (int kt = 0; kt < 16; ++kt){
        int off = kt * 32 + lg2 * 16;
        bf16x8 s0 = *(const bf16x8*)(h1b + ((ln5 * 512 + off) ^ ((ln5 & 15) << 4)));
        bf16x8 s1 = *(const bf16x8*)(h1b + (((32 + ln5) * 512 + off) ^ ((ln5 & 15) << 4)));
        bf16x8 w0 = *(const bf16x8*)(w2f + ((size_t)((kt * 8 + wave * 2    ) * 64 + lane)) * 8);
        bf16x8 w1 = *(const bf16x8*)(w2f + ((size_t)((kt * 8 + wave * 2 + 1) * 64 + lane)) * 8);
        a00 = __builtin_amdgcn_mfma_f32_32x32x16_bf16(w0, s0, a00, 0, 0, 0);
        a01 = __builtin_amdgcn_mfma_f32_32x32x16_bf16(w0, s1, a01, 0, 0, 0);
        a10 = __builtin_amdgcn_mfma_f32_32x32x16_bf16(w1, s0, a10, 0, 0, 0);
        a11 = __builtin_amdgcn_mfma_f32_32x32x16_bf16(w1, s1, a11, 0, 0, 0);
      }
      // epilogue: relu + bias + pack; feat = ntg*32 + g*8 + lg2*4 + j
#pragma unroll
      for (int g = 0; g < 4; ++g){
        int f0 = wave * 64 + g * 8 + lg2 * 4;          // feat-tile 0
        int f1 = f0 + 32;                              // feat-tile 1
        float4 bb0 = *(const float4*)&b2s[f0];
        float4 bb1 = *(const float4*)&b2s[f1];
        {
          float v0 = fmaxf(a00[g*4+0] + bb0.x, 0.f), v1 = fmaxf(a00[g*4+1] + bb0.y, 0.f);
          float v2 = fmaxf(a00[g*4+2] + bb0.z, 0.f), v3 = fmaxf(a00[g*4+3] + bb0.w, 0.f);
          int byte = (ln5 * 512 + f0 * 2) ^ ((ln5 & 15) << 4);
          *(uint2*)(h2b + byte) = make_uint2(cvt_pk_bf16(v0, v1), cvt_pk_bf16(v2, v3));
        }
        {
          float v0 = fmaxf(a01[g*4+0] + bb0.x, 0.f), v1 = fmaxf(a01[g*4+1] + bb0.y, 0.f);
          float v2 = fmaxf(a01[g*4+2] + bb0.z, 0.f), v3 = fmaxf(a01[g*4+3] + bb0.w, 0.f);
          int byte = ((32 + ln5) * 512 + f0 * 2) ^ ((ln5 & 15) << 4);
          *(uint2*)(h2b + byte) = make_uint2(cvt_pk_bf16(v0, v1), cvt_pk_bf16(v2, v3));
        }
        {
          float v0 = fmaxf(a10[g*4+0] + bb1.x, 0.f), v1 = fmaxf(a10[g*4+1] + bb1.y, 0.f);
          float v2 = fmaxf(a10[g*4+2] + bb1.z, 0.f), v3 = fmaxf(a10[g*4+3] + bb1.w, 0.f);
          int byte = (ln5 * 512 + f1 * 2) ^ ((ln5 & 15) << 4);
          *(uint2*)(h2b + byte) = make_uint2(cvt_pk_bf16(v0, v1), cvt_pk_bf16(v2, v3));
        }
        {
          float v0 = fmaxf(a11[g*4+0] + bb1.x, 0.f), v1 = fmaxf(a11[g*4+1] + bb1.y, 0.f);
          float v2 = fmaxf(a11[g*4+2] + bb1.z, 0.f), v3 = fmaxf(a11[g*4+3] + bb1.w, 0.f);
          int byte = ((32 + ln5) * 512 + f1 * 2) ^ ((ln5 & 15) << 4);
          *(uint2*)(h2b + byte) = make_uint2(cvt_pk_bf16(v0, v1), cvt_pk_bf16(v2, v3));
        }
      }
    }
    __syncthreads();

    // ---- stop logit (col 512): 4 threads/row, 64 rows ----
    {
      int row = tid >> 2, f4 = tid & 3;
      float sp = 0.f;
#pragma unroll
      for (int c8 = 0; c8 < 8; ++c8){
        int sl = c8 * 4 + f4;
        int byte = (row * 512 + sl * 16) ^ ((row & 15) << 4);
        uint4 q = *(const uint4*)(h2b + byte);
        unsigned int qq[4] = {q.x, q.y, q.z, q.w};
#pragma unroll
        for (int p = 0; p < 4; ++p){
          int f = sl * 8 + 2 * p;
          sp += bf2f((unsigned short)(qq[p] & 0xFFFFu)) * bf2f(whst_h[f])
              + bf2f((unsigned short)(qq[p] >> 16))     * bf2f(whst_h[f + 1]);
        }
      }
      sp += __shfl_xor(sp, 1);
      sp += __shfl_xor(sp, 2);
      if (f4 == 0){
        int kc = (meta2[t + (row >> 5)][row & 31] >> M_KSH) & 31;
        stopl[row] = (kc == 0) ? NEG_INF : sp + stopbias;
      }
    }

    // ---- Phase C (swapped): lane owns sample ln5 (both steps), 4 passes ----
    {
      int mt  = meta2[t][ln5];
      int mt1 = meta2[t + 1][ln5];
      int arow0 = mt & 1023, arow1 = mt1 & 1023;
      bool g0 = (mt  & M_ALIVE) && !(mt  & M_STOP);
      bool g1 = (mt1 & M_ALIVE) && !(mt1 & M_STOP);
      unsigned full0 = (mt  & M_FULL) ? 1u : 0u;
      unsigned full1 = (mt1 & M_FULL) ? 1u : 0u;
      int pa = (mt & M_NEW) ? arow0 : -1;   // patch col for step t+1 mask
      float sum0 = 0.f, sum1 = 0.f;
#pragma unroll
      for (int p = 0; p < 4; ++p){
        int pt = wave * 4 + p;
        f32x16 a0, a1;
#pragma unroll
        for (int i = 0; i < 16; ++i){ a0[i] = 0.f; a1[i] = 0.f; }
#pragma unroll 4
        for (int kt = 0; kt < 16; ++kt){
          int off = kt * 32 + lg2 * 16;
          bf16x8 b0 = *(const bf16x8*)(h2b + ((ln5 * 512 + off) ^ ((ln5 & 15) << 4)));
          bf16x8 b1_ = *(const bf16x8*)(h2b + (((32 + ln5) * 512 + off) ^ ((ln5 & 15) << 4)));
          bf16x8 w = *(const bf16x8*)(whf + ((size_t)((kt * 16 + pt) * 64 + lane)) * 8);
          a0 = __builtin_amdgcn_mfma_f32_32x32x16_bf16(w, b0, a0, 0, 0, 0);
          a1 = __builtin_amdgcn_mfma_f32_32x32x16_bf16(w, b1_, a1, 0, 0, 0);
        }
        unsigned long long sw = selw[ln5][pt >> 1] >> ((pt & 1) * 32 + lg2 * 4);
        int tr0 = (g0 && (arow0 >> 5) == pt && (((arow0 >> 2) & 1) == lg2))
                  ? ((((arow0 >> 3) & 3) << 2) | (arow0 & 3)) : -1;
        int tr1 = (g1 && (arow1 >> 5) == pt && (((arow1 >> 2) & 1) == lg2))
                  ? ((((arow1 >> 3) & 3) << 2) | (arow1 & 3)) : -1;
        int trp = (pa >= 0 && (pa >> 5) == pt && (((pa >> 2) & 1) == lg2))
                  ? ((((pa >> 3) & 3) << 2) | (pa & 3)) : -1;
        float c0v = 0.f, c0e = 1.f, c1v = 0.f, c1e = 1.f;
#pragma unroll
        for (int g = 0; g < 4; ++g){
          float4 eb = *(const float4*)&ebh[pt * 32 + g * 8 + lg2 * 4];
#pragma unroll
          for (int j = 0; j < 4; ++j){
            int r = g * 4 + j;
            unsigned bit = (unsigned)(sw >> (j + 8 * g)) & 1u;
            float v0 = (bit | full0) ? NEG_INF : a0[r];
            float v1 = ((bit | full1) || (r == trp)) ? NEG_INF : a1[r];
            float e = (j == 0) ? eb.x : (j == 1) ? eb.y : (j == 2) ? eb.z : eb.w;
            sum0 = fmaf(__builtin_amdgcn_exp2f(v0), e, sum0);
            sum1 = fmaf(__builtin_amdgcn_exp2f(v1), e, sum1);
            if (r == tr0){ c0v = v0; c0e = e; }
            if (r == tr1){ c1v = v1; c1e = e; }
          }
        }
        if (tr0 >= 0) chosen[ln5]      = (c0v == NEG_INF) ? NEG_INF : fmaf(c0v, LN2, __logf(c0e));
        if (tr1 >= 0) chosen[32 + ln5] = (c1v == NEG_INF) ? NEG_INF : fmaf(c1v, LN2, __logf(c1e));
      }
      sum0 += __shfl_xor(sum0, 32);
      sum1 += __shfl_xor(sum1, 32);
      if (lg2 == 0){ pred_s[ln5][wave] = sum0; pred_s[32 + ln5][wave] = sum1; }
    }
    __syncthreads();

    // ---- finalize both steps: lse, logpf, selw commit ----
    if (tid < 32){
      int s = tid;
      int mt  = meta2[t][s];
      int mt1 = meta2[t + 1][s];
      {
        float tot = __expf(stopl[s]) + pred_s[s][0] + pred_s[s][1] + pred_s[s][2] + pred_s[s][3];
        float lse = __logf(tot);
        if (mt & M_ALIVE) logpf_s[s] += ((mt & M_STOP) ? stopl[s] : chosen[s]) - lse;
        if (mt & M_NEW){ int a = mt & 1023; selw[s][a >> 6] |= 1ULL << (a & 63); }
      }
      {
        int row = 32 + s;
        float tot = __expf(stopl[row]) + pred_s[row][0] + pred_s[row][1] + pred_s[row][2] + pred_s[row][3];
        float lse = __logf(tot);
        if (mt1 & M_ALIVE) logpf_s[s] += ((mt1 & M_STOP) ? stopl[row] : chosen[row]) - lse;
        if (mt1 & M_NEW){ int a = mt1 & 1023; selw[s][a >> 6] |= 1ULL << (a & 63); }
      }
    }
    __syncthreads();
  } // chunk loop

  if (tid < 32) out[base + tid] = logpf_s[tid];
}

extern "C" void kernel_launch(void* const* d_in, const int* in_sizes, int n_in,
                              void* d_out, int out_size, void* d_ws, size_t ws_size,
                              hipStream_t stream)
{
  const int*   actions = (const int*)d_in[0];
  const float* rp  = (const float*)d_in[1];
  const float* W1  = (const float*)d_in[2];
  const float* b1  = (const float*)d_in[3];
  const float* W2  = (const float*)d_in[4];
  const float* b2  = (const float*)d_in[5];
  const float* Wh  = (const float*)d_in[6];
  const float* bh  = (const float*)d_in[7];
  float* out = (float*)d_out;

  unsigned short* w2f = (unsigned short*)d_ws;          // 65536  bf16 (128 KB)
  unsigned short* whf = w2f + 65536;                    // 131072 bf16 (256 KB)
  float* whstop = (float*)(whf + 131072);               // 256 f32

  prep_kernel<<<97, 256, 0, stream>>>(W2, Wh, w2f, whf, whstop);
  gfn_kernel<<<2048, 256, 0, stream>>>(actions, rp, W1, b1, b2, bh, w2f, whf, whstop, out);
}

// Round 7
// 837.130 us; speedup vs baseline: 2.2162x; 2.2162x over previous
//
#include <hip/hip_runtime.h>

// SubsetGFlowNetTB: 17-step GFlowNet trajectory-balance forward.
// R7 = R5 register discipline + R6 2-step chunking.
// Steps are independent once per-(sample,t) metadata is precomputed (state
// depends only on actions). 9 chunks x 2 steps, 64-row tiles:
//  - Phase B: two SEQUENTIAL passes, 2 accs each (R5's proven no-spill shape);
//    R6's 4-concurrent-acc version spilled ~2GB scratch.
//  - Phase C: one whf fetch serves both row-tiles (2 accs) -> whf L2 traffic
//    halves (13.4 -> 9.4 GB total).
//  - Separate h1/h2 buffers: 4 barriers per 2 steps (R5: 10).

#define NEG_INF (-1000000000.0f)
#define LOG2E 1.4426950408889634f
#define LN2   0.6931471805599453f

// meta2 bits: [9:0] action, [10] alive, [11] stop, [12] isnew, [13] full, [20:16] kcnt
#define M_ALIVE (1 << 10)
#define M_STOP  (1 << 11)
#define M_NEW   (1 << 12)
#define M_FULL  (1 << 13)
#define M_KSH   16

typedef short bf16x8 __attribute__((ext_vector_type(8)));
typedef float f32x16 __attribute__((ext_vector_type(16)));

__device__ __forceinline__ unsigned short f2bf(float x){
  unsigned int u = __float_as_uint(x);
  u = (u + 0x7FFFu + ((u >> 16) & 1u)) >> 16;   // RNE
  return (unsigned short)u;
}
__device__ __forceinline__ float bf2f(unsigned short h){
  return __uint_as_float(((unsigned int)h) << 16);
}
__device__ __forceinline__ unsigned int cvt_pk_bf16(float lo, float hi){
  unsigned int r;
  asm("v_cvt_pk_bf16_f32 %0, %1, %2" : "=v"(r) : "v"(lo), "v"(hi));
  return r;
}

// ---------------------------------------------------------------------------
// Prep: W2 (256x256 f32), Wh (256x513 f32) -> bf16 MFMA fragments.
// Fragment: lane l of tile (kt,ntg) holds M[kt*16+(l>>5)*8+i][ntg*32+(l&31)].
// whf is PRE-SCALED by log2(e) so phase C can use v_exp2 directly.
// ---------------------------------------------------------------------------
__global__ void prep_kernel(const float* __restrict__ W2, const float* __restrict__ Wh,
                            unsigned short* __restrict__ w2f, unsigned short* __restrict__ whf,
                            float* __restrict__ whstop){
  int id = blockIdx.x * 256 + threadIdx.x;
  if (id < 8192){                       // W2 fragments
    int lane = id & 63; int tile = id >> 6;   // tile = kt*8 + ntg
    int ntg = tile & 7, kt = tile >> 3;
    int col = ntg * 32 + (lane & 31);
    int k0  = kt * 16 + (lane >> 5) * 8;
    unsigned int u[4];
#pragma unroll
    for (int p = 0; p < 4; ++p){
      unsigned short lo = f2bf(W2[(k0 + 2*p    ) * 256 + col]);
      unsigned short hi = f2bf(W2[(k0 + 2*p + 1) * 256 + col]);
      u[p] = (unsigned int)lo | ((unsigned int)hi << 16);
    }
    *(uint4*)(w2f + (size_t)id * 8) = make_uint4(u[0], u[1], u[2], u[3]);
  } else if (id < 24576){               // Wh fragments (asset cols 0..511), x log2e
    int id2 = id - 8192;
    int lane = id2 & 63; int tile = id2 >> 6; // tile = kt*16 + ntg
    int ntg = tile & 15, kt = tile >> 4;
    int col = ntg * 32 + (lane & 31);
    int k0  = kt * 16 + (lane >> 5) * 8;
    unsigned int u[4];
#pragma unroll
    for (int p = 0; p < 4; ++p){
      unsigned short lo = f2bf(Wh[(k0 + 2*p    ) * 513 + col] * LOG2E);
      unsigned short hi = f2bf(Wh[(k0 + 2*p + 1) * 513 + col] * LOG2E);
      u[p] = (unsigned int)lo | ((unsigned int)hi << 16);
    }
    *(uint4*)(whf + (size_t)id2 * 8) = make_uint4(u[0], u[1], u[2], u[3]);
  } else if (id < 24832){               // stop column, f32, unscaled
    int k = id - 24576;
    whstop[k] = Wh[k * 513 + 512];
  }
}

// ---------------------------------------------------------------------------
// Fused kernel: 256 threads (4 waves) own 32 samples, 9 chunks x 2 steps.
// h1/h2 tiles [64 rows][256 feats] bf16: rows 0-31 = step t, 32-63 = t+1.
// Byte-XOR swizzle ((row&15)<<4); 32 == 0 mod 16 so (row&15)==(ln5&15).
// ---------------------------------------------------------------------------
__launch_bounds__(256, 2)
__global__ void gfn_kernel(const int* __restrict__ actions, const float* __restrict__ rp,
                           const float* __restrict__ W1, const float* __restrict__ b1,
                           const float* __restrict__ b2, const float* __restrict__ bh,
                           const unsigned short* __restrict__ w2f,
                           const unsigned short* __restrict__ whf,
                           const float* __restrict__ whstop,
                           float* __restrict__ out)
{
  __shared__ alignas(16) unsigned short h1[64 * 256];   // 32 KB
  __shared__ alignas(16) unsigned short h2[64 * 256];   // 32 KB
  __shared__ alignas(16) float c_lds[1024];             // W1 rows 512..514 + b1
  __shared__ alignas(16) float b2s[256];
  __shared__ alignas(16) float ebh[512];                // exp(bh[col]), plain order
  __shared__ alignas(16) unsigned short whst_h[256];    // stop col, bf16
  __shared__ unsigned long long selw[32][9];            // pad 9
  __shared__ float pred_s[64][5];                       // pad 5
  __shared__ float stopl[64];
  __shared__ float chosen[64];
  __shared__ float logpf_s[32];
  __shared__ float rp_s[32];
  __shared__ int   meta2[18][32];

  const int tid  = threadIdx.x;
  const int wave = tid >> 6;            // 0..3
  const int lane = tid & 63;
  const int ln5  = lane & 31;
  const int lg2  = lane >> 5;
  const int base = blockIdx.x * 32;

  // ---- init ----
  for (int i = tid; i < 1024; i += 256){
    int rrow = i >> 8, f = i & 255;
    c_lds[i] = (rrow < 3) ? W1[(512 + rrow) * 256 + f] : b1[f];
  }
  b2s[tid] = b2[tid];
  whst_h[tid] = f2bf(whstop[tid]);
  for (int i = tid; i < 512; i += 256) ebh[i] = __expf(bh[i]);
  const float stopbias = bh[512];
  for (int i = tid; i < 288; i += 256) ((unsigned long long*)selw)[i] = 0ULL;
  int* acts = (int*)h1;                 // stage actions in h1 scratch
  for (int i = tid; i < 544; i += 256) acts[i] = actions[base * 17 + i];
  if (tid < 32){ logpf_s[tid] = 0.f; rp_s[tid] = rp[base + tid]; }
  __syncthreads();

  // ---- state precompute: O(17^2) scan per sample; no GEMM dependency ----
  if (tid < 32){
    int s = tid, k = 0;
    for (int t = 0; t < 17; ++t){
      int a = acts[s * 17 + t];
      bool alive  = (a >= 0);
      bool isstop = (a == 512);
      bool isnew  = alive && (a < 512);
      if (isnew){
        for (int u = 0; u < t; ++u) if (acts[s * 17 + u] == a){ isnew = false; break; }
      }
      meta2[t][s] = (a & 1023) | (alive ? M_ALIVE : 0) | (isstop ? M_STOP : 0)
                  | (isnew ? M_NEW : 0) | ((k >= 16) ? M_FULL : 0) | (k << M_KSH);
      if (isnew) ++k;
    }
    meta2[17][s] = 1023 | ((k >= 16) ? M_FULL : 0) | (k << M_KSH);  // dummy step
  }
  float S[32];
#pragma unroll
  for (int j = 0; j < 32; ++j) S[j] = 0.f;
  __syncthreads();

  char* h1b = (char*)h1;
  char* h2b = (char*)h2;

#pragma unroll 1
  for (int c = 0; c < 9; ++c){
    const int t = c * 2;

    // ---- Phase A: h1 rows for steps t and t+1; thread=(4 feats, 8 samples) ----
    {
      const float4 ck4 = *(const float4*)&c_lds[lane * 4];
      const float4 ct4 = *(const float4*)&c_lds[256 + lane * 4];
      const float4 cr4 = *(const float4*)&c_lds[512 + lane * 4];
      const float4 cb4 = *(const float4*)&c_lds[768 + lane * 4];
      float tf = (float)t;
      float c00 = cb4.x + tf * ct4.x, c01 = cb4.y + tf * ct4.y;
      float c02 = cb4.z + tf * ct4.z, c03 = cb4.w + tf * ct4.w;
      float c10 = c00 + ct4.x, c11 = c01 + ct4.y, c12 = c02 + ct4.z, c13 = c03 + ct4.w;
#pragma unroll
      for (int s8 = 0; s8 < 8; ++s8){
        int s = wave * 8 + s8;
        float rv = rp_s[s];
        int m0 = meta2[t][s];
        float kf = (float)((m0 >> M_KSH) & 31);
        {
          float v0 = fmaxf(S[s8*4+0] + kf * ck4.x + rv * cr4.x + c00, 0.f);
          float v1 = fmaxf(S[s8*4+1] + kf * ck4.y + rv * cr4.y + c01, 0.f);
          float v2 = fmaxf(S[s8*4+2] + kf * ck4.z + rv * cr4.z + c02, 0.f);
          float v3 = fmaxf(S[s8*4+3] + kf * ck4.w + rv * cr4.w + c03, 0.f);
          int byte = (s * 512 + lane * 8) ^ ((s & 15) << 4);
          *(uint2*)(h1b + byte) = make_uint2(cvt_pk_bf16(v0, v1), cvt_pk_bf16(v2, v3));
        }
        if (m0 & M_NEW){
          int a = m0 & 1023;
          float4 w = *(const float4*)(W1 + (size_t)a * 256 + lane * 4);
          S[s8*4+0] += w.x; S[s8*4+1] += w.y; S[s8*4+2] += w.z; S[s8*4+3] += w.w;
        }
        int m1 = meta2[t + 1][s];
        float kf1 = (float)((m1 >> M_KSH) & 31);
        {
          float v0 = fmaxf(S[s8*4+0] + kf1 * ck4.x + rv * cr4.x + c10, 0.f);
          float v1 = fmaxf(S[s8*4+1] + kf1 * ck4.y + rv * cr4.y + c11, 0.f);
          float v2 = fmaxf(S[s8*4+2] + kf1 * ck4.z + rv * cr4.z + c12, 0.f);
          float v3 = fmaxf(S[s8*4+3] + kf1 * ck4.w + rv * cr4.w + c13, 0.f);
          int byte = ((32 + s) * 512 + lane * 8) ^ ((s & 15) << 4);
          *(uint2*)(h1b + byte) = make_uint2(cvt_pk_bf16(v0, v1), cvt_pk_bf16(v2, v3));
        }
        if (m1 & M_NEW){
          int a = m1 & 1023;
          float4 w = *(const float4*)(W1 + (size_t)a * 256 + lane * 4);
          S[s8*4+0] += w.x; S[s8*4+1] += w.y; S[s8*4+2] += w.z; S[s8*4+3] += w.w;
        }
      }
    }
    __syncthreads();

    // ---- Phase B (swapped): D'[feat][row]; TWO sequential passes, 2 accs each
    //      (R5's proven no-spill register shape; 4 concurrent accs spilled in R6)
#pragma unroll 1
    for (int q = 0; q < 2; ++q){
      f32x16 aB0, aB1;
#pragma unroll
      for (int i = 0; i < 16; ++i){ aB0[i] = 0.f; aB1[i] = 0.f; }
#pragma unroll 4
      for (int kt = 0; kt < 16; ++kt){
        int off = kt * 32 + lg2 * 16;
        int rr = q * 32 + ln5;
        bf16x8 sf = *(const bf16x8*)(h1b + ((rr * 512 + off) ^ ((ln5 & 15) << 4)));
        bf16x8 w0 = *(const bf16x8*)(w2f + ((size_t)((kt * 8 + wave * 2    ) * 64 + lane)) * 8);
        bf16x8 w1 = *(const bf16x8*)(w2f + ((size_t)((kt * 8 + wave * 2 + 1) * 64 + lane)) * 8);
        aB0 = __builtin_amdgcn_mfma_f32_32x32x16_bf16(w0, sf, aB0, 0, 0, 0);
        aB1 = __builtin_amdgcn_mfma_f32_32x32x16_bf16(w1, sf, aB1, 0, 0, 0);
      }
      int rr = q * 32 + ln5;
#pragma unroll
      for (int g = 0; g < 4; ++g){
        int f0 = wave * 64 + g * 8 + lg2 * 4;
        int f1 = f0 + 32;
        float4 bb0 = *(const float4*)&b2s[f0];
        float4 bb1 = *(const float4*)&b2s[f1];
        {
          float v0 = fmaxf(aB0[g*4+0] + bb0.x, 0.f), v1 = fmaxf(aB0[g*4+1] + bb0.y, 0.f);
          float v2 = fmaxf(aB0[g*4+2] + bb0.z, 0.f), v3 = fmaxf(aB0[g*4+3] + bb0.w, 0.f);
          int byte = (rr * 512 + f0 * 2) ^ ((ln5 & 15) << 4);
          *(uint2*)(h2b + byte) = make_uint2(cvt_pk_bf16(v0, v1), cvt_pk_bf16(v2, v3));
        }
        {
          float v0 = fmaxf(aB1[g*4+0] + bb1.x, 0.f), v1 = fmaxf(aB1[g*4+1] + bb1.y, 0.f);
          float v2 = fmaxf(aB1[g*4+2] + bb1.z, 0.f), v3 = fmaxf(aB1[g*4+3] + bb1.w, 0.f);
          int byte = (rr * 512 + f1 * 2) ^ ((ln5 & 15) << 4);
          *(uint2*)(h2b + byte) = make_uint2(cvt_pk_bf16(v0, v1), cvt_pk_bf16(v2, v3));
        }
      }
    }
    __syncthreads();

    // ---- stop logit (col 512): 4 threads/row, 64 rows ----
    {
      int row = tid >> 2, f4 = tid & 3;
      float sp = 0.f;
#pragma unroll
      for (int c8 = 0; c8 < 8; ++c8){
        int sl = c8 * 4 + f4;
        int byte = (row * 512 + sl * 16) ^ ((row & 15) << 4);
        uint4 q = *(const uint4*)(h2b + byte);
        unsigned int qq[4] = {q.x, q.y, q.z, q.w};
#pragma unroll
        for (int p = 0; p < 4; ++p){
          int f = sl * 8 + 2 * p;
          sp += bf2f((unsigned short)(qq[p] & 0xFFFFu)) * bf2f(whst_h[f])
              + bf2f((unsigned short)(qq[p] >> 16))     * bf2f(whst_h[f + 1]);
        }
      }
      sp += __shfl_xor(sp, 1);
      sp += __shfl_xor(sp, 2);
      if (f4 == 0){
        int kc = (meta2[t + (row >> 5)][row & 31] >> M_KSH) & 31;
        stopl[row] = (kc == 0) ? NEG_INF : sp + stopbias;
      }
    }

    // ---- Phase C (swapped): lane owns sample ln5 (both steps); one whf fetch
    //      serves both row-tiles. 4 passes, 2 accs each.
    {
      int mt  = meta2[t][ln5];
      int mt1 = meta2[t + 1][ln5];
      int arow0 = mt & 1023, arow1 = mt1 & 1023;
      bool g0 = (mt  & M_ALIVE) && !(mt  & M_STOP);
      bool g1 = (mt1 & M_ALIVE) && !(mt1 & M_STOP);
      unsigned full0 = (mt  & M_FULL) ? 1u : 0u;
      unsigned full1 = (mt1 & M_FULL) ? 1u : 0u;
      int pa = (mt & M_NEW) ? arow0 : -1;   // patch col for step t+1 mask
      float sum0 = 0.f, sum1 = 0.f;
#pragma unroll 1
      for (int p = 0; p < 4; ++p){
        int pt = wave * 4 + p;
        f32x16 a0, a1;
#pragma unroll
        for (int i = 0; i < 16; ++i){ a0[i] = 0.f; a1[i] = 0.f; }
#pragma unroll 4
        for (int kt = 0; kt < 16; ++kt){
          int off = kt * 32 + lg2 * 16;
          bf16x8 b0 = *(const bf16x8*)(h2b + ((ln5 * 512 + off) ^ ((ln5 & 15) << 4)));
          bf16x8 b1_ = *(const bf16x8*)(h2b + (((32 + ln5) * 512 + off) ^ ((ln5 & 15) << 4)));
          bf16x8 w = *(const bf16x8*)(whf + ((size_t)((kt * 16 + pt) * 64 + lane)) * 8);
          a0 = __builtin_amdgcn_mfma_f32_32x32x16_bf16(w, b0, a0, 0, 0, 0);
          a1 = __builtin_amdgcn_mfma_f32_32x32x16_bf16(w, b1_, a1, 0, 0, 0);
        }
        unsigned long long sw = selw[ln5][pt >> 1] >> ((pt & 1) * 32 + lg2 * 4);
        int tr0 = (g0 && (arow0 >> 5) == pt && (((arow0 >> 2) & 1) == lg2))
                  ? ((((arow0 >> 3) & 3) << 2) | (arow0 & 3)) : -1;
        int tr1 = (g1 && (arow1 >> 5) == pt && (((arow1 >> 2) & 1) == lg2))
                  ? ((((arow1 >> 3) & 3) << 2) | (arow1 & 3)) : -1;
        int trp = (pa >= 0 && (pa >> 5) == pt && (((pa >> 2) & 1) == lg2))
                  ? ((((pa >> 3) & 3) << 2) | (pa & 3)) : -1;
        float c0v = 0.f, c0e = 1.f, c1v = 0.f, c1e = 1.f;
#pragma unroll
        for (int g = 0; g < 4; ++g){
          float4 eb = *(const float4*)&ebh[pt * 32 + g * 8 + lg2 * 4];
#pragma unroll
          for (int j = 0; j < 4; ++j){
            int r = g * 4 + j;
            unsigned bit = (unsigned)(sw >> (j + 8 * g)) & 1u;
            float v0 = (bit | full0) ? NEG_INF : a0[r];
            float v1 = ((bit | full1) || (r == trp)) ? NEG_INF : a1[r];
            float e = (j == 0) ? eb.x : (j == 1) ? eb.y : (j == 2) ? eb.z : eb.w;
            sum0 = fmaf(__builtin_amdgcn_exp2f(v0), e, sum0);
            sum1 = fmaf(__builtin_amdgcn_exp2f(v1), e, sum1);
            if (r == tr0){ c0v = v0; c0e = e; }
            if (r == tr1){ c1v = v1; c1e = e; }
          }
        }
        if (tr0 >= 0) chosen[ln5]      = (c0v == NEG_INF) ? NEG_INF : fmaf(c0v, LN2, __logf(c0e));
        if (tr1 >= 0) chosen[32 + ln5] = (c1v == NEG_INF) ? NEG_INF : fmaf(c1v, LN2, __logf(c1e));
      }
      sum0 += __shfl_xor(sum0, 32);
      sum1 += __shfl_xor(sum1, 32);
      if (lg2 == 0){ pred_s[ln5][wave] = sum0; pred_s[32 + ln5][wave] = sum1; }
    }
    __syncthreads();

    // ---- finalize both steps: lse, logpf, selw commit ----
    if (tid < 32){
      int s = tid;
      int mt  = meta2[t][s];
      int mt1 = meta2[t + 1][s];
      {
        float tot = __expf(stopl[s]) + pred_s[s][0] + pred_s[s][1] + pred_s[s][2] + pred_s[s][3];
        float lse = __logf(tot);
        if (mt & M_ALIVE) logpf_s[s] += ((mt & M_STOP) ? stopl[s] : chosen[s]) - lse;
        if (mt & M_NEW){ int a = mt & 1023; selw[s][a >> 6] |= 1ULL << (a & 63); }
      }
      {
        int row = 32 + s;
        float tot = __expf(stopl[row]) + pred_s[row][0] + pred_s[row][1] + pred_s[row][2] + pred_s[row][3];
        float lse = __logf(tot);
        if (mt1 & M_ALIVE) logpf_s[s] += ((mt1 & M_STOP) ? stopl[row] : chosen[row]) - lse;
        if (mt1 & M_NEW){ int a = mt1 & 1023; selw[s][a >> 6] |= 1ULL << (a & 63); }
      }
    }
    __syncthreads();
  } // chunk loop

  if (tid < 32) out[base + tid] = logpf_s[tid];
}

extern "C" void kernel_launch(void* const* d_in, const int* in_sizes, int n_in,
                              void* d_out, int out_size, void* d_ws, size_t ws_size,
                              hipStream_t stream)
{
  const int*   actions = (const int*)d_in[0];
  const float* rp  = (const float*)d_in[1];
  const float* W1  = (const float*)d_in[2];
  const float* b1  = (const float*)d_in[3];
  const float* W2  = (const float*)d_in[4];
  const float* b2  = (const float*)d_in[5];
  const float* Wh  = (const float*)d_in[6];
  const float* bh  = (const float*)d_in[7];
  float* out = (float*)d_out;

  unsigned short* w2f = (unsigned short*)d_ws;          // 65536  bf16 (128 KB)
  unsigned short* whf = w2f + 65536;                    // 131072 bf16 (256 KB)
  float* whstop = (float*)(whf + 131072);               // 256 f32

  prep_kernel<<<97, 256, 0, stream>>>(W2, Wh, w2f, whf, whstop);
  gfn_kernel<<<2048, 256, 0, stream>>>(actions, rp, W1, b1, b2, bh, w2f, whf, whstop, out);
}

// Round 8
// 729.966 us; speedup vs baseline: 2.5416x; 1.1468x over previous
//
#include <hip/hip_runtime.h>

// SubsetGFlowNetTB: 17-step GFlowNet trajectory-balance forward.
// R8 = R7 + occupancy unlock: 3 blocks/CU (12 waves) instead of 2 (8 waves).
//  - LDS 80 -> ~47 KB: single h buffer; phase B = 2 sequential passes, each
//    {read h1 rows [32q,+32), barrier, overwrite same rows with h2}.
//  - Register diet: S[32]f32 -> Spk[16] packed bf16 (unpack=1 op/val; repack
//    cvt_pk only on accepted actions, <=16 roundings per sample total).
//  - __launch_bounds__(256,3): 170-reg budget, no forced spill (R2/R4 lesson:
//    never force below natural demand ~135).

#define NEG_INF (-1000000000.0f)
#define LOG2E 1.4426950408889634f
#define LN2   0.6931471805599453f

// meta2 bits: [9:0] action, [10] alive, [11] stop, [12] isnew, [13] full, [20:16] kcnt
#define M_ALIVE (1 << 10)
#define M_STOP  (1 << 11)
#define M_NEW   (1 << 12)
#define M_FULL  (1 << 13)
#define M_KSH   16

typedef short bf16x8 __attribute__((ext_vector_type(8)));
typedef float f32x16 __attribute__((ext_vector_type(16)));

__device__ __forceinline__ unsigned short f2bf(float x){
  unsigned int u = __float_as_uint(x);
  u = (u + 0x7FFFu + ((u >> 16) & 1u)) >> 16;   // RNE
  return (unsigned short)u;
}
__device__ __forceinline__ float bf2f(unsigned short h){
  return __uint_as_float(((unsigned int)h) << 16);
}
__device__ __forceinline__ unsigned int cvt_pk_bf16(float lo, float hi){
  unsigned int r;
  asm("v_cvt_pk_bf16_f32 %0, %1, %2" : "=v"(r) : "v"(lo), "v"(hi));
  return r;
}

// ---------------------------------------------------------------------------
// Prep: W2 (256x256 f32), Wh (256x513 f32) -> bf16 MFMA fragments.
// Fragment: lane l of tile (kt,ntg) holds M[kt*16+(l>>5)*8+i][ntg*32+(l&31)].
// whf is PRE-SCALED by log2(e) so phase C can use v_exp2 directly.
// ---------------------------------------------------------------------------
__global__ void prep_kernel(const float* __restrict__ W2, const float* __restrict__ Wh,
                            unsigned short* __restrict__ w2f, unsigned short* __restrict__ whf,
                            float* __restrict__ whstop){
  int id = blockIdx.x * 256 + threadIdx.x;
  if (id < 8192){                       // W2 fragments
    int lane = id & 63; int tile = id >> 6;   // tile = kt*8 + ntg
    int ntg = tile & 7, kt = tile >> 3;
    int col = ntg * 32 + (lane & 31);
    int k0  = kt * 16 + (lane >> 5) * 8;
    unsigned int u[4];
#pragma unroll
    for (int p = 0; p < 4; ++p){
      unsigned short lo = f2bf(W2[(k0 + 2*p    ) * 256 + col]);
      unsigned short hi = f2bf(W2[(k0 + 2*p + 1) * 256 + col]);
      u[p] = (unsigned int)lo | ((unsigned int)hi << 16);
    }
    *(uint4*)(w2f + (size_t)id * 8) = make_uint4(u[0], u[1], u[2], u[3]);
  } else if (id < 24576){               // Wh fragments (asset cols 0..511), x log2e
    int id2 = id - 8192;
    int lane = id2 & 63; int tile = id2 >> 6; // tile = kt*16 + ntg
    int ntg = tile & 15, kt = tile >> 4;
    int col = ntg * 32 + (lane & 31);
    int k0  = kt * 16 + (lane >> 5) * 8;
    unsigned int u[4];
#pragma unroll
    for (int p = 0; p < 4; ++p){
      unsigned short lo = f2bf(Wh[(k0 + 2*p    ) * 513 + col] * LOG2E);
      unsigned short hi = f2bf(Wh[(k0 + 2*p + 1) * 513 + col] * LOG2E);
      u[p] = (unsigned int)lo | ((unsigned int)hi << 16);
    }
    *(uint4*)(whf + (size_t)id2 * 8) = make_uint4(u[0], u[1], u[2], u[3]);
  } else if (id < 24832){               // stop column, f32, unscaled
    int k = id - 24576;
    whstop[k] = Wh[k * 513 + 512];
  }
}

// ---------------------------------------------------------------------------
// Fused kernel: 256 threads (4 waves) own 32 samples, 9 chunks x 2 steps.
// Single h tile [64 rows][256 feats] bf16 (h1 then h2 per 32-row pass);
// rows 0-31 = step t, 32-63 = t+1. Byte-XOR swizzle ((row&15)<<4).
// ---------------------------------------------------------------------------
__launch_bounds__(256, 3)
__global__ void gfn_kernel(const int* __restrict__ actions, const float* __restrict__ rp,
                           const float* __restrict__ W1, const float* __restrict__ b1,
                           const float* __restrict__ b2, const float* __restrict__ bh,
                           const unsigned short* __restrict__ w2f,
                           const unsigned short* __restrict__ whf,
                           const float* __restrict__ whstop,
                           float* __restrict__ out)
{
  __shared__ alignas(16) unsigned short h[64 * 256];    // 32 KB (h1, then h2)
  __shared__ alignas(16) float c_lds[1024];             // W1 rows 512..514 + b1
  __shared__ alignas(16) float b2s[256];
  __shared__ alignas(16) float ebh[512];                // exp(bh[col]), plain order
  __shared__ alignas(16) unsigned short whst_h[256];    // stop col, bf16
  __shared__ unsigned long long selw[32][9];            // pad 9
  __shared__ float pred_s[64][5];                       // pad 5
  __shared__ float stopl[64];
  __shared__ float chosen[64];
  __shared__ float logpf_s[32];
  __shared__ float rp_s[32];
  __shared__ int   meta2[18][32];

  const int tid  = threadIdx.x;
  const int wave = tid >> 6;            // 0..3
  const int lane = tid & 63;
  const int ln5  = lane & 31;
  const int lg2  = lane >> 5;
  const int base = blockIdx.x * 32;

  // ---- init ----
  for (int i = tid; i < 1024; i += 256){
    int rrow = i >> 8, f = i & 255;
    c_lds[i] = (rrow < 3) ? W1[(512 + rrow) * 256 + f] : b1[f];
  }
  b2s[tid] = b2[tid];
  whst_h[tid] = f2bf(whstop[tid]);
  for (int i = tid; i < 512; i += 256) ebh[i] = __expf(bh[i]);
  const float stopbias = bh[512];
  for (int i = tid; i < 288; i += 256) ((unsigned long long*)selw)[i] = 0ULL;
  int* acts = (int*)h;                  // stage actions in h scratch
  for (int i = tid; i < 544; i += 256) acts[i] = actions[base * 17 + i];
  if (tid < 32){ logpf_s[tid] = 0.f; rp_s[tid] = rp[base + tid]; }
  __syncthreads();

  // ---- state precompute: O(17^2) scan per sample; no GEMM dependency ----
  if (tid < 32){
    int s = tid, k = 0;
    for (int t = 0; t < 17; ++t){
      int a = acts[s * 17 + t];
      bool alive  = (a >= 0);
      bool isstop = (a == 512);
      bool isnew  = alive && (a < 512);
      if (isnew){
        for (int u = 0; u < t; ++u) if (acts[s * 17 + u] == a){ isnew = false; break; }
      }
      meta2[t][s] = (a & 1023) | (alive ? M_ALIVE : 0) | (isstop ? M_STOP : 0)
                  | (isnew ? M_NEW : 0) | ((k >= 16) ? M_FULL : 0) | (k << M_KSH);
      if (isnew) ++k;
    }
    meta2[17][s] = 1023 | ((k >= 16) ? M_FULL : 0) | (k << M_KSH);  // dummy step
  }
  // packed layer-1 running sum: Spk[2*s8+{0,1}] = bf16x2 of feats {0,1},{2,3}
  unsigned int Spk[16];
#pragma unroll
  for (int j = 0; j < 16; ++j) Spk[j] = 0u;
  __syncthreads();

  char* hb = (char*)h;

#pragma unroll 1
  for (int c = 0; c < 9; ++c){
    const int t = c * 2;

    // ---- Phase A: h1 rows for steps t and t+1; thread=(4 feats, 8 samples) ----
    {
      const float4 ck4 = *(const float4*)&c_lds[lane * 4];
      const float4 ct4 = *(const float4*)&c_lds[256 + lane * 4];
      const float4 cr4 = *(const float4*)&c_lds[512 + lane * 4];
      const float4 cb4 = *(const float4*)&c_lds[768 + lane * 4];
      float tf = (float)t;
      float c00 = cb4.x + tf * ct4.x, c01 = cb4.y + tf * ct4.y;
      float c02 = cb4.z + tf * ct4.z, c03 = cb4.w + tf * ct4.w;
      float c10 = c00 + ct4.x, c11 = c01 + ct4.y, c12 = c02 + ct4.z, c13 = c03 + ct4.w;
#pragma unroll
      for (int s8 = 0; s8 < 8; ++s8){
        int s = wave * 8 + s8;
        float rv = rp_s[s];
        int m0 = meta2[t][s];
        int m1 = meta2[t + 1][s];
        unsigned int pk0 = Spk[s8 * 2], pk1 = Spk[s8 * 2 + 1];
        float S0 = __uint_as_float(pk0 << 16);
        float S1 = __uint_as_float(pk0 & 0xFFFF0000u);
        float S2 = __uint_as_float(pk1 << 16);
        float S3 = __uint_as_float(pk1 & 0xFFFF0000u);
        float kf = (float)((m0 >> M_KSH) & 31);
        {
          float v0 = fmaxf(S0 + kf * ck4.x + rv * cr4.x + c00, 0.f);
          float v1 = fmaxf(S1 + kf * ck4.y + rv * cr4.y + c01, 0.f);
          float v2 = fmaxf(S2 + kf * ck4.z + rv * cr4.z + c02, 0.f);
          float v3 = fmaxf(S3 + kf * ck4.w + rv * cr4.w + c03, 0.f);
          int byte = (s * 512 + lane * 8) ^ ((s & 15) << 4);
          *(uint2*)(hb + byte) = make_uint2(cvt_pk_bf16(v0, v1), cvt_pk_bf16(v2, v3));
        }
        if (m0 & M_NEW){
          int a = m0 & 1023;
          float4 w = *(const float4*)(W1 + (size_t)a * 256 + lane * 4);
          S0 += w.x; S1 += w.y; S2 += w.z; S3 += w.w;
        }
        float kf1 = (float)((m1 >> M_KSH) & 31);
        {
          float v0 = fmaxf(S0 + kf1 * ck4.x + rv * cr4.x + c10, 0.f);
          float v1 = fmaxf(S1 + kf1 * ck4.y + rv * cr4.y + c11, 0.f);
          float v2 = fmaxf(S2 + kf1 * ck4.z + rv * cr4.z + c12, 0.f);
          float v3 = fmaxf(S3 + kf1 * ck4.w + rv * cr4.w + c13, 0.f);
          int byte = ((32 + s) * 512 + lane * 8) ^ ((s & 15) << 4);
          *(uint2*)(hb + byte) = make_uint2(cvt_pk_bf16(v0, v1), cvt_pk_bf16(v2, v3));
        }
        if (m1 & M_NEW){
          int a = m1 & 1023;
          float4 w = *(const float4*)(W1 + (size_t)a * 256 + lane * 4);
          S0 += w.x; S1 += w.y; S2 += w.z; S3 += w.w;
        }
        if ((m0 | m1) & M_NEW){
          Spk[s8 * 2]     = cvt_pk_bf16(S0, S1);
          Spk[s8 * 2 + 1] = cvt_pk_bf16(S2, S3);
        }
      }
    }
    __syncthreads();

    // ---- Phase B (swapped): D'[feat][row]; 2 sequential passes over the
    //      SINGLE h buffer: read h1 rows [32q,+32), barrier, overwrite with h2.
#pragma unroll 1
    for (int q = 0; q < 2; ++q){
      f32x16 aB0, aB1;
#pragma unroll
      for (int i = 0; i < 16; ++i){ aB0[i] = 0.f; aB1[i] = 0.f; }
#pragma unroll 4
      for (int kt = 0; kt < 16; ++kt){
        int off = kt * 32 + lg2 * 16;
        int rr = q * 32 + ln5;
        bf16x8 sf = *(const bf16x8*)(hb + ((rr * 512 + off) ^ ((ln5 & 15) << 4)));
        bf16x8 w0 = *(const bf16x8*)(w2f + ((size_t)((kt * 8 + wave * 2    ) * 64 + lane)) * 8);
        bf16x8 w1 = *(const bf16x8*)(w2f + ((size_t)((kt * 8 + wave * 2 + 1) * 64 + lane)) * 8);
        aB0 = __builtin_amdgcn_mfma_f32_32x32x16_bf16(w0, sf, aB0, 0, 0, 0);
        aB1 = __builtin_amdgcn_mfma_f32_32x32x16_bf16(w1, sf, aB1, 0, 0, 0);
      }
      __syncthreads();   // all waves done reading h1 rows [32q,+32)
      int rr = q * 32 + ln5;
#pragma unroll
      for (int g = 0; g < 4; ++g){
        int f0 = wave * 64 + g * 8 + lg2 * 4;
        int f1 = f0 + 32;
        float4 bb0 = *(const float4*)&b2s[f0];
        float4 bb1 = *(const float4*)&b2s[f1];
        {
          float v0 = fmaxf(aB0[g*4+0] + bb0.x, 0.f), v1 = fmaxf(aB0[g*4+1] + bb0.y, 0.f);
          float v2 = fmaxf(aB0[g*4+2] + bb0.z, 0.f), v3 = fmaxf(aB0[g*4+3] + bb0.w, 0.f);
          int byte = (rr * 512 + f0 * 2) ^ ((ln5 & 15) << 4);
          *(uint2*)(hb + byte) = make_uint2(cvt_pk_bf16(v0, v1), cvt_pk_bf16(v2, v3));
        }
        {
          float v0 = fmaxf(aB1[g*4+0] + bb1.x, 0.f), v1 = fmaxf(aB1[g*4+1] + bb1.y, 0.f);
          float v2 = fmaxf(aB1[g*4+2] + bb1.z, 0.f), v3 = fmaxf(aB1[g*4+3] + bb1.w, 0.f);
          int byte = (rr * 512 + f1 * 2) ^ ((ln5 & 15) << 4);
          *(uint2*)(hb + byte) = make_uint2(cvt_pk_bf16(v0, v1), cvt_pk_bf16(v2, v3));
        }
      }
    }
    __syncthreads();   // h2 fully written

    // ---- stop logit (col 512): 4 threads/row, 64 rows ----
    {
      int row = tid >> 2, f4 = tid & 3;
      float sp = 0.f;
#pragma unroll
      for (int c8 = 0; c8 < 8; ++c8){
        int sl = c8 * 4 + f4;
        int byte = (row * 512 + sl * 16) ^ ((row & 15) << 4);
        uint4 q = *(const uint4*)(hb + byte);
        unsigned int qq[4] = {q.x, q.y, q.z, q.w};
#pragma unroll
        for (int p = 0; p < 4; ++p){
          int f = sl * 8 + 2 * p;
          sp += bf2f((unsigned short)(qq[p] & 0xFFFFu)) * bf2f(whst_h[f])
              + bf2f((unsigned short)(qq[p] >> 16))     * bf2f(whst_h[f + 1]);
        }
      }
      sp += __shfl_xor(sp, 1);
      sp += __shfl_xor(sp, 2);
      if (f4 == 0){
        int kc = (meta2[t + (row >> 5)][row & 31] >> M_KSH) & 31;
        stopl[row] = (kc == 0) ? NEG_INF : sp + stopbias;
      }
    }

    // ---- Phase C (swapped): lane owns sample ln5 (both steps); one whf fetch
    //      serves both row-tiles. 4 passes, 2 accs each.
    {
      int mt  = meta2[t][ln5];
      int mt1 = meta2[t + 1][ln5];
      int arow0 = mt & 1023, arow1 = mt1 & 1023;
      bool g0 = (mt  & M_ALIVE) && !(mt  & M_STOP);
      bool g1 = (mt1 & M_ALIVE) && !(mt1 & M_STOP);
      unsigned full0 = (mt  & M_FULL) ? 1u : 0u;
      unsigned full1 = (mt1 & M_FULL) ? 1u : 0u;
      int pa = (mt & M_NEW) ? arow0 : -1;   // patch col for step t+1 mask
      float sum0 = 0.f, sum1 = 0.f;
#pragma unroll 1
      for (int p = 0; p < 4; ++p){
        int pt = wave * 4 + p;
        f32x16 a0, a1;
#pragma unroll
        for (int i = 0; i < 16; ++i){ a0[i] = 0.f; a1[i] = 0.f; }
#pragma unroll 4
        for (int kt = 0; kt < 16; ++kt){
          int off = kt * 32 + lg2 * 16;
          bf16x8 b0 = *(const bf16x8*)(hb + ((ln5 * 512 + off) ^ ((ln5 & 15) << 4)));
          bf16x8 b1_ = *(const bf16x8*)(hb + (((32 + ln5) * 512 + off) ^ ((ln5 & 15) << 4)));
          bf16x8 w = *(const bf16x8*)(whf + ((size_t)((kt * 16 + pt) * 64 + lane)) * 8);
          a0 = __builtin_amdgcn_mfma_f32_32x32x16_bf16(w, b0, a0, 0, 0, 0);
          a1 = __builtin_amdgcn_mfma_f32_32x32x16_bf16(w, b1_, a1, 0, 0, 0);
        }
        unsigned long long sw = selw[ln5][pt >> 1] >> ((pt & 1) * 32 + lg2 * 4);
        int tr0 = (g0 && (arow0 >> 5) == pt && (((arow0 >> 2) & 1) == lg2))
                  ? ((((arow0 >> 3) & 3) << 2) | (arow0 & 3)) : -1;
        int tr1 = (g1 && (arow1 >> 5) == pt && (((arow1 >> 2) & 1) == lg2))
                  ? ((((arow1 >> 3) & 3) << 2) | (arow1 & 3)) : -1;
        int trp = (pa >= 0 && (pa >> 5) == pt && (((pa >> 2) & 1) == lg2))
                  ? ((((pa >> 3) & 3) << 2) | (pa & 3)) : -1;
        float c0v = 0.f, c0e = 1.f, c1v = 0.f, c1e = 1.f;
#pragma unroll
        for (int g = 0; g < 4; ++g){
          float4 eb = *(const float4*)&ebh[pt * 32 + g * 8 + lg2 * 4];
#pragma unroll
          for (int j = 0; j < 4; ++j){
            int r = g * 4 + j;
            unsigned bit = (unsigned)(sw >> (j + 8 * g)) & 1u;
            float v0 = (bit | full0) ? NEG_INF : a0[r];
            float v1 = ((bit | full1) || (r == trp)) ? NEG_INF : a1[r];
            float e = (j == 0) ? eb.x : (j == 1) ? eb.y : (j == 2) ? eb.z : eb.w;
            sum0 = fmaf(__builtin_amdgcn_exp2f(v0), e, sum0);
            sum1 = fmaf(__builtin_amdgcn_exp2f(v1), e, sum1);
            if (r == tr0){ c0v = v0; c0e = e; }
            if (r == tr1){ c1v = v1; c1e = e; }
          }
        }
        if (tr0 >= 0) chosen[ln5]      = (c0v == NEG_INF) ? NEG_INF : fmaf(c0v, LN2, __logf(c0e));
        if (tr1 >= 0) chosen[32 + ln5] = (c1v == NEG_INF) ? NEG_INF : fmaf(c1v, LN2, __logf(c1e));
      }
      sum0 += __shfl_xor(sum0, 32);
      sum1 += __shfl_xor(sum1, 32);
      if (lg2 == 0){ pred_s[ln5][wave] = sum0; pred_s[32 + ln5][wave] = sum1; }
    }
    __syncthreads();

    // ---- finalize both steps: lse, logpf, selw commit ----
    if (tid < 32){
      int s = tid;
      int mt  = meta2[t][s];
      int mt1 = meta2[t + 1][s];
      {
        float tot = __expf(stopl[s]) + pred_s[s][0] + pred_s[s][1] + pred_s[s][2] + pred_s[s][3];
        float lse = __logf(tot);
        if (mt & M_ALIVE) logpf_s[s] += ((mt & M_STOP) ? stopl[s] : chosen[s]) - lse;
        if (mt & M_NEW){ int a = mt & 1023; selw[s][a >> 6] |= 1ULL << (a & 63); }
      }
      {
        int row = 32 + s;
        float tot = __expf(stopl[row]) + pred_s[row][0] + pred_s[row][1] + pred_s[row][2] + pred_s[row][3];
        float lse = __logf(tot);
        if (mt1 & M_ALIVE) logpf_s[s] += ((mt1 & M_STOP) ? stopl[row] : chosen[row]) - lse;
        if (mt1 & M_NEW){ int a = mt1 & 1023; selw[s][a >> 6] |= 1ULL << (a & 63); }
      }
    }
    __syncthreads();
  } // chunk loop

  if (tid < 32) out[base + tid] = logpf_s[tid];
}

extern "C" void kernel_launch(void* const* d_in, const int* in_sizes, int n_in,
                              void* d_out, int out_size, void* d_ws, size_t ws_size,
                              hipStream_t stream)
{
  const int*   actions = (const int*)d_in[0];
  const float* rp  = (const float*)d_in[1];
  const float* W1  = (const float*)d_in[2];
  const float* b1  = (const float*)d_in[3];
  const float* W2  = (const float*)d_in[4];
  const float* b2  = (const float*)d_in[5];
  const float* Wh  = (const float*)d_in[6];
  const float* bh  = (const float*)d_in[7];
  float* out = (float*)d_out;

  unsigned short* w2f = (unsigned short*)d_ws;          // 65536  bf16 (128 KB)
  unsigned short* whf = w2f + 65536;                    // 131072 bf16 (256 KB)
  float* whstop = (float*)(whf + 131072);               // 256 f32

  prep_kernel<<<97, 256, 0, stream>>>(W2, Wh, w2f, whf, whstop);
  gfn_kernel<<<2048, 256, 0, stream>>>(actions, rp, W1, b1, b2, bh, w2f, whf, whstop, out);
}